// Round 4
// baseline (5889.646 us; speedup 1.0000x reference)
//
#include <hip/hip_runtime.h>
#include <hip/hip_bf16.h>
#include <math.h>

// Problem constants (from reference): D = ATTN = 128, N_NODE = 100000.
#define DIM 128
#define N_NODE_C 100000

// ---------------------------------------------------------------------------
// Small projections: qrW[b] = rela_embed[q_rel[b]] @ Wqr_w + Wqr_b   (B rows)
//                    hrW[r] = rela_embed[r]        @ Wr             (RV rows)
// One block (128 threads) per output row.
// ---------------------------------------------------------------------------
__global__ __launch_bounds__(128) void proj_small(
    const int* __restrict__ q_rel,
    const float* __restrict__ rela,
    const float* __restrict__ Wqr_w,
    const float* __restrict__ Wqr_b,
    const float* __restrict__ Wr,
    float* __restrict__ qrW,
    float* __restrict__ hrW,
    int B)
{
    __shared__ float emb[DIM];
    const int blk = blockIdx.x;
    const int j   = threadIdx.x;

    const float* W;
    float* out;
    float bias = 0.f;
    int row;
    if (blk < B) {
        row  = q_rel[blk];
        W    = Wqr_w;
        out  = qrW + (size_t)blk * DIM;
        bias = Wqr_b[j];
    } else {
        row = blk - B;
        W   = Wr;
        out = hrW + (size_t)(blk - B) * DIM;
    }
    emb[j] = rela[(size_t)row * DIM + j];
    __syncthreads();

    float acc = bias;
#pragma unroll 8
    for (int k = 0; k < DIM; ++k)
        acc += emb[k] * W[k * DIM + j];
    out[j] = acc;
}

// ---------------------------------------------------------------------------
// C[M x 128] = A[M x 128] @ W[128 x 128]   (fp32)
// 64-row tile per block, 256 threads, 8x4 register tile per thread.
// Safe for in-place use (C == A): each block stages its own 64 rows in LDS
// (barrier-separated from the writes), and blocks touch disjoint rows.
// ---------------------------------------------------------------------------
__global__ __launch_bounds__(256) void gemm_n128(
    const float* A,
    const float* __restrict__ W,
    float* C,
    int M)
{
    __shared__ __align__(16) float Alds[64][DIM];
    __shared__ __align__(16) float Wlds[32][DIM];

    const int t    = threadIdx.x;
    const int row0 = blockIdx.x * 64;
    const int tx   = t & 31;   // col group: cols tx*4 .. tx*4+3
    const int ty   = t >> 5;   // row group: rows ty*8 .. ty*8+7

    // Load A tile: 64x128 floats = 8 float4 per thread (coalesced).
    {
#pragma unroll
        for (int p = 0; p < 8; ++p) {
            int idx = p * 1024 + t * 4;          // float index within tile
            int r   = idx >> 7;
            int c   = idx & 127;
            int gr  = row0 + r;
            if (gr >= M) gr = M - 1;             // clamp (M % 64 == 0 in practice)
            *(float4*)&Alds[r][c] = *(const float4*)&A[(size_t)gr * DIM + c];
        }
    }

    float acc[8][4] = {};

#pragma unroll
    for (int kk = 0; kk < 4; ++kk) {
        // Load W chunk rows [kk*32, kk*32+32): 4 float4 per thread.
        {
            const float* Wg = W + (size_t)kk * 32 * DIM;
#pragma unroll
            for (int p = 0; p < 4; ++p) {
                int idx = p * 1024 + t * 4;
                *(float4*)&Wlds[idx >> 7][idx & 127] = *(const float4*)&Wg[idx];
            }
        }
        __syncthreads();
#pragma unroll
        for (int k = 0; k < 32; ++k) {
            float4 w = *(float4*)&Wlds[k][tx * 4];
#pragma unroll
            for (int i = 0; i < 8; ++i) {
                float a = Alds[ty * 8 + i][kk * 32 + k];   // FIX: K-chunk offset
                acc[i][0] += a * w.x;
                acc[i][1] += a * w.y;
                acc[i][2] += a * w.z;
                acc[i][3] += a * w.w;
            }
        }
        __syncthreads();
    }

    // Write back (after all reads of this block's rows -> in-place safe).
#pragma unroll
    for (int i = 0; i < 8; ++i) {
        int gr = row0 + ty * 8 + i;
        if (gr < M) {
            float4 v = make_float4(acc[i][0], acc[i][1], acc[i][2], acc[i][3]);
            *(float4*)&C[(size_t)gr * DIM + tx * 4] = v;
        }
    }
}

// ---------------------------------------------------------------------------
// Per-edge kernel: one 64-lane wave per edge, 2 columns per lane.
//   pre  = relu(hsW[sub] + hrW[rel] + qrW[r_idx])        (bias folded in qrW)
//   alpha= sigmoid(pre . walpha_w + walpha_b)
//   atomicAdd(agg[obj], alpha * (hidden[sub] + rela[rel]))
// MODE 0: hsW precomputed.  MODE 1: compute hidden[sub] @ Ws inline (fallback).
// ---------------------------------------------------------------------------
template <int MODE>
__global__ __launch_bounds__(256) void edge_kernel(
    const int* __restrict__ edges,
    const float* __restrict__ hidden,
    const float* __restrict__ rela,
    const float* __restrict__ Ws,
    const float* __restrict__ hsW,
    const float* __restrict__ qrW,
    const float* __restrict__ hrW,
    const float* __restrict__ walpha_w,
    const float* __restrict__ walpha_b,
    float* __restrict__ agg,
    float* __restrict__ alpha_out,
    int E)
{
    const int widx = threadIdx.x >> 6;
    const int lane = threadIdx.x & 63;
    const int e    = blockIdx.x * 4 + widx;
    const bool valid = (e < E);
    const int ec   = valid ? e : 0;

    const int r_idx = edges[(size_t)ec * 6 + 0];
    const int rel   = edges[(size_t)ec * 6 + 2];
    const int sub   = edges[(size_t)ec * 6 + 4];
    const int obj   = edges[(size_t)ec * 6 + 5];

    const int j = lane * 2;

    const float2 hv = *(const float2*)&hidden[(size_t)sub * DIM + j];
    const float2 rv = *(const float2*)&rela[(size_t)rel * DIM + j];

    float p0, p1;
    if (MODE == 0) {
        float2 a = *(const float2*)&hsW[(size_t)sub * DIM + j];
        p0 = a.x;
        p1 = a.y;
    } else {
        __shared__ float hrow[4][DIM];
        *(float2*)&hrow[widx][j] = hv;
        __syncthreads();
        p0 = 0.f;
        p1 = 0.f;
#pragma unroll 4
        for (int k = 0; k < DIM; ++k) {
            float hk  = hrow[widx][k];
            float2 w2 = *(const float2*)&Ws[k * DIM + j];
            p0 += hk * w2.x;
            p1 += hk * w2.y;
        }
    }

    const float2 b2 = *(const float2*)&hrW[(size_t)rel * DIM + j];
    const float2 c2 = *(const float2*)&qrW[(size_t)r_idx * DIM + j];
    p0 = fmaxf(p0 + b2.x + c2.x, 0.f);
    p1 = fmaxf(p1 + b2.y + c2.y, 0.f);

    const float2 ww = *(const float2*)&walpha_w[j];
    float s = p0 * ww.x + p1 * ww.y;
#pragma unroll
    for (int off = 32; off >= 1; off >>= 1)
        s += __shfl_xor(s, off, 64);

    const float alpha = 1.f / (1.f + expf(-(s + walpha_b[0])));

    if (valid) {
        const float m0 = alpha * (hv.x + rv.x);
        const float m1 = alpha * (hv.y + rv.y);
        atomicAdd(&agg[(size_t)obj * DIM + j], m0);
        atomicAdd(&agg[(size_t)obj * DIM + j + 1], m1);
        if (lane == 0) alpha_out[e] = alpha;
    }
}

// ---------------------------------------------------------------------------
// sampled_nodes_idx = (nodes[:,1] > -1) & (nodes[:,1] < N_NODE + 1)  -> 1.0/0.0
// ---------------------------------------------------------------------------
__global__ __launch_bounds__(256) void nodes_kernel(
    const int* __restrict__ nodes, float* __restrict__ out, int N)
{
    int i = blockIdx.x * 256 + threadIdx.x;
    if (i < N) {
        int v = nodes[(size_t)i * 2 + 1];
        out[i] = (v > -1 && v < N_NODE_C + 1) ? 1.f : 0.f;
    }
}

// ---------------------------------------------------------------------------
extern "C" void kernel_launch(void* const* d_in, const int* in_sizes, int n_in,
                              void* d_out, int out_size, void* d_ws, size_t ws_size,
                              hipStream_t stream)
{
    const int*   q_rel    = (const int*)d_in[1];
    const float* hidden   = (const float*)d_in[2];
    const int*   edges    = (const int*)d_in[3];
    const int*   nodes    = (const int*)d_in[4];
    const float* rela     = (const float*)d_in[5];
    const float* Ws       = (const float*)d_in[6];
    const float* Wr       = (const float*)d_in[7];
    const float* Wqr_w    = (const float*)d_in[8];
    const float* Wqr_b    = (const float*)d_in[9];
    const float* walpha_w = (const float*)d_in[10];
    const float* walpha_b = (const float*)d_in[11];
    const float* Wh       = (const float*)d_in[12];

    const int B  = in_sizes[1];
    const int N  = in_sizes[2] / DIM;
    const int E  = in_sizes[3] / 6;
    const int RV = in_sizes[5] / DIM;

    float* out       = (float*)d_out;
    float* agg       = out;                          // N*128 (segment-sum, then in-place GEMM)
    float* alpha_out = out + (size_t)N * DIM;        // E
    float* samp      = alpha_out + (size_t)E;        // N

    float* qrW = (float*)d_ws;                       // B x 128
    float* hrW = qrW + (size_t)B * DIM;              // RV x 128
    float* hsW = hrW + (size_t)RV * DIM;             // N x 128 (optional)

    const size_t need_small = ((size_t)B + (size_t)RV) * DIM * sizeof(float);
    const size_t need_full  = need_small + (size_t)N * DIM * sizeof(float);
    const bool precomp = (ws_size >= need_full);

    // Zero the segment-sum region (atomics accumulate into it; must be zeroed
    // every call since the harness doesn't re-poison between replays).
    hipMemsetAsync(agg, 0, (size_t)N * DIM * sizeof(float), stream);

    proj_small<<<B + RV, 128, 0, stream>>>(q_rel, rela, Wqr_w, Wqr_b, Wr, qrW, hrW, B);

    if (precomp) {
        gemm_n128<<<(N + 63) / 64, 256, 0, stream>>>(hidden, Ws, hsW, N);
        edge_kernel<0><<<(E + 3) / 4, 256, 0, stream>>>(
            edges, hidden, rela, Ws, hsW, qrW, hrW, walpha_w, walpha_b,
            agg, alpha_out, E);
    } else {
        edge_kernel<1><<<(E + 3) / 4, 256, 0, stream>>>(
            edges, hidden, rela, Ws, hsW, qrW, hrW, walpha_w, walpha_b,
            agg, alpha_out, E);
    }

    // hidden_new = agg @ Wh, in place over d_out[0 : N*128].
    gemm_n128<<<(N + 63) / 64, 256, 0, stream>>>(agg, Wh, out, N);

    nodes_kernel<<<(N + 255) / 256, 256, 0, stream>>>(nodes, samp, N);
}

// Round 5
// 545.468 us; speedup vs baseline: 10.7974x; 10.7974x over previous
//
#include <hip/hip_runtime.h>
#include <hip/hip_bf16.h>
#include <math.h>

// Problem constants (from reference): D = ATTN = 128, N_NODE = 100000.
#define DIM 128
#define N_NODE_C 100000

// ---------------------------------------------------------------------------
// Small projections: qrW[b] = rela_embed[q_rel[b]] @ Wqr_w + Wqr_b   (B rows)
//                    hrW[r] = rela_embed[r]        @ Wr             (RV rows)
// One block (128 threads) per output row.
// ---------------------------------------------------------------------------
__global__ __launch_bounds__(128) void proj_small(
    const int* __restrict__ q_rel,
    const float* __restrict__ rela,
    const float* __restrict__ Wqr_w,
    const float* __restrict__ Wqr_b,
    const float* __restrict__ Wr,
    float* __restrict__ qrW,
    float* __restrict__ hrW,
    int B)
{
    __shared__ float emb[DIM];
    const int blk = blockIdx.x;
    const int j   = threadIdx.x;

    const float* W;
    float* out;
    float bias = 0.f;
    int row;
    if (blk < B) {
        row  = q_rel[blk];
        W    = Wqr_w;
        out  = qrW + (size_t)blk * DIM;
        bias = Wqr_b[j];
    } else {
        row = blk - B;
        W   = Wr;
        out = hrW + (size_t)(blk - B) * DIM;
    }
    emb[j] = rela[(size_t)row * DIM + j];
    __syncthreads();

    float acc = bias;
#pragma unroll 8
    for (int k = 0; k < DIM; ++k)
        acc += emb[k] * W[k * DIM + j];
    out[j] = acc;
}

// ---------------------------------------------------------------------------
// C[M x 128] = A[M x 128] @ W[128 x 128]   (fp32)
// 64-row tile per block, 256 threads, 8x4 register tile per thread.
// k-step-4 inner loop with float4 LDS reads; unroll capped to keep the live
// set ~90 VGPR (round-4 version fully unrolled 128 k-steps -> 256 VGPR +
// scratch spills -> 7.7 GB HBM traffic per dispatch).
// Safe for in-place use (C == A): each block stages its own 64 rows in LDS
// (barrier-separated from the writes), and blocks touch disjoint rows.
// ---------------------------------------------------------------------------
__global__ __launch_bounds__(256, 3) void gemm_n128(
    const float* A,
    const float* __restrict__ W,
    float* C,
    int M)
{
    __shared__ __align__(16) float Alds[64][DIM];
    __shared__ __align__(16) float Wlds[32][DIM];

    const int t    = threadIdx.x;
    const int row0 = blockIdx.x * 64;
    const int tx   = t & 31;   // col group: cols tx*4 .. tx*4+3
    const int ty   = t >> 5;   // row group: rows ty*8 .. ty*8+7

    // Load A tile: 64x128 floats = 8 float4 per thread (coalesced).
#pragma unroll
    for (int p = 0; p < 8; ++p) {
        int idx = p * 1024 + t * 4;          // float index within tile
        int r   = idx >> 7;
        int c   = idx & 127;
        int gr  = row0 + r;
        if (gr >= M) gr = M - 1;             // clamp (M % 64 == 0 in practice)
        *(float4*)&Alds[r][c] = *(const float4*)&A[(size_t)gr * DIM + c];
    }

    float acc[8][4] = {};

    for (int kk = 0; kk < 4; ++kk) {         // NOT unrolled: keeps W chunks cold
        __syncthreads();                     // Alds ready / Wlds drained
        {
            const float* Wg = W + (size_t)kk * 32 * DIM;
#pragma unroll
            for (int p = 0; p < 4; ++p) {
                int idx = p * 1024 + t * 4;
                *(float4*)&Wlds[idx >> 7][idx & 127] = *(const float4*)&Wg[idx];
            }
        }
        __syncthreads();

#pragma unroll 2
        for (int k4 = 0; k4 < 32; k4 += 4) {
            const float4 w0 = *(const float4*)&Wlds[k4 + 0][tx * 4];
            const float4 w1 = *(const float4*)&Wlds[k4 + 1][tx * 4];
            const float4 w2 = *(const float4*)&Wlds[k4 + 2][tx * 4];
            const float4 w3 = *(const float4*)&Wlds[k4 + 3][tx * 4];
#pragma unroll
            for (int i = 0; i < 8; ++i) {
                const float4 a = *(const float4*)&Alds[ty * 8 + i][kk * 32 + k4];
                acc[i][0] = fmaf(a.w, w3.x, fmaf(a.z, w2.x, fmaf(a.y, w1.x, fmaf(a.x, w0.x, acc[i][0]))));
                acc[i][1] = fmaf(a.w, w3.y, fmaf(a.z, w2.y, fmaf(a.y, w1.y, fmaf(a.x, w0.y, acc[i][1]))));
                acc[i][2] = fmaf(a.w, w3.z, fmaf(a.z, w2.z, fmaf(a.y, w1.z, fmaf(a.x, w0.z, acc[i][2]))));
                acc[i][3] = fmaf(a.w, w3.w, fmaf(a.z, w2.w, fmaf(a.y, w1.w, fmaf(a.x, w0.w, acc[i][3]))));
            }
        }
    }
    __syncthreads();                         // all Alds reads done (in-place safety)

    // Write back (blocks own disjoint rows -> in-place safe).
#pragma unroll
    for (int i = 0; i < 8; ++i) {
        int gr = row0 + ty * 8 + i;
        if (gr < M) {
            float4 v = make_float4(acc[i][0], acc[i][1], acc[i][2], acc[i][3]);
            *(float4*)&C[(size_t)gr * DIM + tx * 4] = v;
        }
    }
}

// ---------------------------------------------------------------------------
// Per-edge kernel: one 64-lane wave per edge, 2 columns per lane.
//   pre  = relu(hsW[sub] + hrW[rel] + qrW[r_idx])        (bias folded in qrW)
//   alpha= sigmoid(pre . walpha_w + walpha_b)
//   atomicAdd(agg[obj], alpha * (hidden[sub] + rela[rel]))
// MODE 0: hsW precomputed.  MODE 1: compute hidden[sub] @ Ws inline (fallback).
// ---------------------------------------------------------------------------
template <int MODE>
__global__ __launch_bounds__(256) void edge_kernel(
    const int* __restrict__ edges,
    const float* __restrict__ hidden,
    const float* __restrict__ rela,
    const float* __restrict__ Ws,
    const float* __restrict__ hsW,
    const float* __restrict__ qrW,
    const float* __restrict__ hrW,
    const float* __restrict__ walpha_w,
    const float* __restrict__ walpha_b,
    float* __restrict__ agg,
    float* __restrict__ alpha_out,
    int E)
{
    const int widx = threadIdx.x >> 6;
    const int lane = threadIdx.x & 63;
    const int e    = blockIdx.x * 4 + widx;
    const bool valid = (e < E);
    const int ec   = valid ? e : 0;

    const int r_idx = edges[(size_t)ec * 6 + 0];
    const int rel   = edges[(size_t)ec * 6 + 2];
    const int sub   = edges[(size_t)ec * 6 + 4];
    const int obj   = edges[(size_t)ec * 6 + 5];

    const int j = lane * 2;

    const float2 hv = *(const float2*)&hidden[(size_t)sub * DIM + j];
    const float2 rv = *(const float2*)&rela[(size_t)rel * DIM + j];

    float p0, p1;
    if (MODE == 0) {
        float2 a = *(const float2*)&hsW[(size_t)sub * DIM + j];
        p0 = a.x;
        p1 = a.y;
    } else {
        __shared__ float hrow[4][DIM];
        *(float2*)&hrow[widx][j] = hv;
        __syncthreads();
        p0 = 0.f;
        p1 = 0.f;
#pragma unroll 4
        for (int k = 0; k < DIM; ++k) {
            float hk  = hrow[widx][k];
            float2 w2 = *(const float2*)&Ws[k * DIM + j];
            p0 += hk * w2.x;
            p1 += hk * w2.y;
        }
    }

    const float2 b2 = *(const float2*)&hrW[(size_t)rel * DIM + j];
    const float2 c2 = *(const float2*)&qrW[(size_t)r_idx * DIM + j];
    p0 = fmaxf(p0 + b2.x + c2.x, 0.f);
    p1 = fmaxf(p1 + b2.y + c2.y, 0.f);

    const float2 ww = *(const float2*)&walpha_w[j];
    float s = p0 * ww.x + p1 * ww.y;
#pragma unroll
    for (int off = 32; off >= 1; off >>= 1)
        s += __shfl_xor(s, off, 64);

    const float alpha = 1.f / (1.f + expf(-(s + walpha_b[0])));

    if (valid) {
        const float m0 = alpha * (hv.x + rv.x);
        const float m1 = alpha * (hv.y + rv.y);
        atomicAdd(&agg[(size_t)obj * DIM + j], m0);
        atomicAdd(&agg[(size_t)obj * DIM + j + 1], m1);
        if (lane == 0) alpha_out[e] = alpha;
    }
}

// ---------------------------------------------------------------------------
// sampled_nodes_idx = (nodes[:,1] > -1) & (nodes[:,1] < N_NODE + 1)  -> 1.0/0.0
// ---------------------------------------------------------------------------
__global__ __launch_bounds__(256) void nodes_kernel(
    const int* __restrict__ nodes, float* __restrict__ out, int N)
{
    int i = blockIdx.x * 256 + threadIdx.x;
    if (i < N) {
        int v = nodes[(size_t)i * 2 + 1];
        out[i] = (v > -1 && v < N_NODE_C + 1) ? 1.f : 0.f;
    }
}

// ---------------------------------------------------------------------------
extern "C" void kernel_launch(void* const* d_in, const int* in_sizes, int n_in,
                              void* d_out, int out_size, void* d_ws, size_t ws_size,
                              hipStream_t stream)
{
    const int*   q_rel    = (const int*)d_in[1];
    const float* hidden   = (const float*)d_in[2];
    const int*   edges    = (const int*)d_in[3];
    const int*   nodes    = (const int*)d_in[4];
    const float* rela     = (const float*)d_in[5];
    const float* Ws       = (const float*)d_in[6];
    const float* Wr       = (const float*)d_in[7];
    const float* Wqr_w    = (const float*)d_in[8];
    const float* Wqr_b    = (const float*)d_in[9];
    const float* walpha_w = (const float*)d_in[10];
    const float* walpha_b = (const float*)d_in[11];
    const float* Wh       = (const float*)d_in[12];

    const int B  = in_sizes[1];
    const int N  = in_sizes[2] / DIM;
    const int E  = in_sizes[3] / 6;
    const int RV = in_sizes[5] / DIM;

    float* out       = (float*)d_out;
    float* agg       = out;                          // N*128 (segment-sum, then in-place GEMM)
    float* alpha_out = out + (size_t)N * DIM;        // E
    float* samp      = alpha_out + (size_t)E;        // N

    float* qrW = (float*)d_ws;                       // B x 128
    float* hrW = qrW + (size_t)B * DIM;              // RV x 128
    float* hsW = hrW + (size_t)RV * DIM;             // N x 128 (optional)

    const size_t need_small = ((size_t)B + (size_t)RV) * DIM * sizeof(float);
    const size_t need_full  = need_small + (size_t)N * DIM * sizeof(float);
    const bool precomp = (ws_size >= need_full);

    // Zero the segment-sum region (atomics accumulate into it; must be zeroed
    // every call since the harness doesn't re-poison between replays).
    hipMemsetAsync(agg, 0, (size_t)N * DIM * sizeof(float), stream);

    proj_small<<<B + RV, 128, 0, stream>>>(q_rel, rela, Wqr_w, Wqr_b, Wr, qrW, hrW, B);

    if (precomp) {
        gemm_n128<<<(N + 63) / 64, 256, 0, stream>>>(hidden, Ws, hsW, N);
        edge_kernel<0><<<(E + 3) / 4, 256, 0, stream>>>(
            edges, hidden, rela, Ws, hsW, qrW, hrW, walpha_w, walpha_b,
            agg, alpha_out, E);
    } else {
        edge_kernel<1><<<(E + 3) / 4, 256, 0, stream>>>(
            edges, hidden, rela, Ws, hsW, qrW, hrW, walpha_w, walpha_b,
            agg, alpha_out, E);
    }

    // hidden_new = agg @ Wh, in place over d_out[0 : N*128].
    gemm_n128<<<(N + 63) / 64, 256, 0, stream>>>(agg, Wh, out, N);

    nodes_kernel<<<(N + 255) / 256, 256, 0, stream>>>(nodes, samp, N);
}

// Round 6
// 413.604 us; speedup vs baseline: 14.2398x; 1.3188x over previous
//
#include <hip/hip_runtime.h>
#include <hip/hip_bf16.h>
#include <math.h>

// Problem constants (from reference): D = ATTN = 128, N_NODE = 100000.
#define DIM 128
#define N_NODE_C 100000

// ---------------------------------------------------------------------------
// Small projections: qrW[b] = rela_embed[q_rel[b]] @ Wqr_w + Wqr_b   (B rows)
//                    hrW[r] = rela_embed[r]        @ Wr             (RV rows)
// ---------------------------------------------------------------------------
__global__ __launch_bounds__(128) void proj_small(
    const int* __restrict__ q_rel,
    const float* __restrict__ rela,
    const float* __restrict__ Wqr_w,
    const float* __restrict__ Wqr_b,
    const float* __restrict__ Wr,
    float* __restrict__ qrW,
    float* __restrict__ hrW,
    int B)
{
    __shared__ float emb[DIM];
    const int blk = blockIdx.x;
    const int j   = threadIdx.x;

    const float* W;
    float* out;
    float bias = 0.f;
    int row;
    if (blk < B) {
        row  = q_rel[blk];
        W    = Wqr_w;
        out  = qrW + (size_t)blk * DIM;
        bias = Wqr_b[j];
    } else {
        row = blk - B;
        W   = Wr;
        out = hrW + (size_t)(blk - B) * DIM;
    }
    emb[j] = rela[(size_t)row * DIM + j];
    __syncthreads();

    float acc = bias;
#pragma unroll 8
    for (int k = 0; k < DIM; ++k)
        acc += emb[k] * W[k * DIM + j];
    out[j] = acc;
}

// ---------------------------------------------------------------------------
// C[M x 128] = A[M x 128] @ W[128 x 128]   (fp32). Round-5 version (no spill).
// In-place safe (C == A): block stages its 64 rows in LDS, disjoint rows.
// ---------------------------------------------------------------------------
__global__ __launch_bounds__(256, 3) void gemm_n128(
    const float* A,
    const float* __restrict__ W,
    float* C,
    int M)
{
    __shared__ __align__(16) float Alds[64][DIM];
    __shared__ __align__(16) float Wlds[32][DIM];

    const int t    = threadIdx.x;
    const int row0 = blockIdx.x * 64;
    const int tx   = t & 31;
    const int ty   = t >> 5;

#pragma unroll
    for (int p = 0; p < 8; ++p) {
        int idx = p * 1024 + t * 4;
        int r   = idx >> 7;
        int c   = idx & 127;
        int gr  = row0 + r;
        if (gr >= M) gr = M - 1;
        *(float4*)&Alds[r][c] = *(const float4*)&A[(size_t)gr * DIM + c];
    }

    float acc[8][4] = {};

    for (int kk = 0; kk < 4; ++kk) {
        __syncthreads();
        {
            const float* Wg = W + (size_t)kk * 32 * DIM;
#pragma unroll
            for (int p = 0; p < 4; ++p) {
                int idx = p * 1024 + t * 4;
                *(float4*)&Wlds[idx >> 7][idx & 127] = *(const float4*)&Wg[idx];
            }
        }
        __syncthreads();

#pragma unroll 2
        for (int k4 = 0; k4 < 32; k4 += 4) {
            const float4 w0 = *(const float4*)&Wlds[k4 + 0][tx * 4];
            const float4 w1 = *(const float4*)&Wlds[k4 + 1][tx * 4];
            const float4 w2 = *(const float4*)&Wlds[k4 + 2][tx * 4];
            const float4 w3 = *(const float4*)&Wlds[k4 + 3][tx * 4];
#pragma unroll
            for (int i = 0; i < 8; ++i) {
                const float4 a = *(const float4*)&Alds[ty * 8 + i][kk * 32 + k4];
                acc[i][0] = fmaf(a.w, w3.x, fmaf(a.z, w2.x, fmaf(a.y, w1.x, fmaf(a.x, w0.x, acc[i][0]))));
                acc[i][1] = fmaf(a.w, w3.y, fmaf(a.z, w2.y, fmaf(a.y, w1.y, fmaf(a.x, w0.y, acc[i][1]))));
                acc[i][2] = fmaf(a.w, w3.z, fmaf(a.z, w2.z, fmaf(a.y, w1.z, fmaf(a.x, w0.z, acc[i][2]))));
                acc[i][3] = fmaf(a.w, w3.w, fmaf(a.z, w2.w, fmaf(a.y, w1.w, fmaf(a.x, w0.w, acc[i][3]))));
            }
        }
    }
    __syncthreads();

#pragma unroll
    for (int i = 0; i < 8; ++i) {
        int gr = row0 + ty * 8 + i;
        if (gr < M) {
            float4 v = make_float4(acc[i][0], acc[i][1], acc[i][2], acc[i][3]);
            *(float4*)&C[(size_t)gr * DIM + tx * 4] = v;
        }
    }
}

// ---------------------------------------------------------------------------
// Counting sort by obj: hist -> exclusive scan (3 kernels) -> scatter.
// ---------------------------------------------------------------------------
__global__ __launch_bounds__(256) void hist_kernel(
    const int* __restrict__ edges, int* __restrict__ deg, int E)
{
    int i = blockIdx.x * 256 + threadIdx.x;
    if (i < E) atomicAdd(&deg[edges[(size_t)i * 6 + 5]], 1);
}

// Block-local exclusive scan: 256 threads x 8 items = 2048 items per block.
__global__ __launch_bounds__(256) void scan1_kernel(
    const int* __restrict__ in, int* __restrict__ out,
    int* __restrict__ bsum, int n)
{
    __shared__ int ts[256];
    const int tid  = threadIdx.x;
    const int base = blockIdx.x * 2048 + tid * 8;

    int v[8];
    int run = 0;
#pragma unroll
    for (int i = 0; i < 8; ++i) {
        int x = (base + i < n) ? in[base + i] : 0;
        v[i] = run;                 // thread-local exclusive
        run += x;
    }
    ts[tid] = run;
    __syncthreads();
    for (int off = 1; off < 256; off <<= 1) {
        int x = (tid >= off) ? ts[tid - off] : 0;
        __syncthreads();
        ts[tid] += x;
        __syncthreads();
    }
    const int excl = ts[tid] - run; // exclusive over preceding threads
#pragma unroll
    for (int i = 0; i < 8; ++i)
        if (base + i < n) out[base + i] = v[i] + excl;
    if (tid == 255) bsum[blockIdx.x] = ts[255];
}

// Serial exclusive scan of block sums (nb ~ 98; trivial).
__global__ void scan2_kernel(int* __restrict__ bsum, int nb)
{
    if (blockIdx.x == 0 && threadIdx.x == 0) {
        int run = 0;
        for (int i = 0; i < nb; ++i) { int x = bsum[i]; bsum[i] = run; run += x; }
    }
}

// Add per-block offsets; duplicate into cursor for the scatter pass.
__global__ __launch_bounds__(256) void scan3_kernel(
    int* __restrict__ offs, int* __restrict__ cursor,
    const int* __restrict__ bsum, int n)
{
    int i = blockIdx.x * 256 + threadIdx.x;
    if (i < n) {
        int v = offs[i] + bsum[i >> 11];   // 2048 items per scan1 block
        offs[i]   = v;
        cursor[i] = v;
    }
}

__global__ __launch_bounds__(256) void scatter_kernel(
    const int* __restrict__ edges, int* __restrict__ cursor,
    int* __restrict__ sorted, int E)
{
    int i = blockIdx.x * 256 + threadIdx.x;
    if (i < E) {
        int obj = edges[(size_t)i * 6 + 5];
        int pos = atomicAdd(&cursor[obj], 1);
        sorted[pos] = i;
    }
}

// ---------------------------------------------------------------------------
// Pull-style aggregation: one 64-lane wave per node, 2 columns per lane.
// For each incident edge: alpha = sigmoid(relu(hsW[sub]+hrW[rel]+qrW[r]).w+b),
// acc += alpha*(hidden[sub]+rela[rel]); single non-atomic row store.
// Degree-0 nodes write zeros (replaces the 102 MB memset).
// ---------------------------------------------------------------------------
__global__ __launch_bounds__(256) void node_agg_kernel(
    const int* __restrict__ edges,
    const float* __restrict__ hidden,
    const float* __restrict__ rela,
    const float* __restrict__ hsW,
    const float* __restrict__ qrW,
    const float* __restrict__ hrW,
    const float* __restrict__ walpha_w,
    const float* __restrict__ walpha_b,
    const int* __restrict__ deg,
    const int* __restrict__ offs,
    const int* __restrict__ sorted,
    float* __restrict__ agg,
    float* __restrict__ alpha_out,
    int N)
{
    const int widx = threadIdx.x >> 6;
    const int lane = threadIdx.x & 63;
    const int o    = blockIdx.x * 4 + widx;
    if (o >= N) return;

    const int j = lane * 2;
    const int d = deg[o];
    const int s = offs[o];

    const float2 ww = *(const float2*)&walpha_w[j];
    const float  wb = walpha_b[0];

    float a0 = 0.f, a1 = 0.f;
    for (int k = 0; k < d; ++k) {
        const int e     = sorted[s + k];
        const int r_idx = edges[(size_t)e * 6 + 0];
        const int rel   = edges[(size_t)e * 6 + 2];
        const int sub   = edges[(size_t)e * 6 + 4];

        const float2 hv = *(const float2*)&hidden[(size_t)sub * DIM + j];
        const float2 rv = *(const float2*)&rela[(size_t)rel * DIM + j];
        const float2 pw = *(const float2*)&hsW[(size_t)sub * DIM + j];
        const float2 b2 = *(const float2*)&hrW[(size_t)rel * DIM + j];
        const float2 c2 = *(const float2*)&qrW[(size_t)r_idx * DIM + j];

        float p0 = fmaxf(pw.x + b2.x + c2.x, 0.f);
        float p1 = fmaxf(pw.y + b2.y + c2.y, 0.f);

        float sdot = p0 * ww.x + p1 * ww.y;
#pragma unroll
        for (int off = 32; off >= 1; off >>= 1)
            sdot += __shfl_xor(sdot, off, 64);

        const float alpha = 1.f / (1.f + expf(-(sdot + wb)));

        a0 += alpha * (hv.x + rv.x);
        a1 += alpha * (hv.y + rv.y);
        if (lane == 0) alpha_out[e] = alpha;
    }
    *(float2*)&agg[(size_t)o * DIM + j] = make_float2(a0, a1);
}

// ---------------------------------------------------------------------------
// Fallback (round-5) push-style edge kernel with f32 atomics.
// ---------------------------------------------------------------------------
template <int MODE>
__global__ __launch_bounds__(256) void edge_kernel(
    const int* __restrict__ edges,
    const float* __restrict__ hidden,
    const float* __restrict__ rela,
    const float* __restrict__ Ws,
    const float* __restrict__ hsW,
    const float* __restrict__ qrW,
    const float* __restrict__ hrW,
    const float* __restrict__ walpha_w,
    const float* __restrict__ walpha_b,
    float* __restrict__ agg,
    float* __restrict__ alpha_out,
    int E)
{
    const int widx = threadIdx.x >> 6;
    const int lane = threadIdx.x & 63;
    const int e    = blockIdx.x * 4 + widx;
    const bool valid = (e < E);
    const int ec   = valid ? e : 0;

    const int r_idx = edges[(size_t)ec * 6 + 0];
    const int rel   = edges[(size_t)ec * 6 + 2];
    const int sub   = edges[(size_t)ec * 6 + 4];
    const int obj   = edges[(size_t)ec * 6 + 5];

    const int j = lane * 2;

    const float2 hv = *(const float2*)&hidden[(size_t)sub * DIM + j];
    const float2 rv = *(const float2*)&rela[(size_t)rel * DIM + j];

    float p0, p1;
    if (MODE == 0) {
        float2 a = *(const float2*)&hsW[(size_t)sub * DIM + j];
        p0 = a.x;
        p1 = a.y;
    } else {
        __shared__ float hrow[4][DIM];
        *(float2*)&hrow[widx][j] = hv;
        __syncthreads();
        p0 = 0.f;
        p1 = 0.f;
#pragma unroll 4
        for (int k = 0; k < DIM; ++k) {
            float hk  = hrow[widx][k];
            float2 w2 = *(const float2*)&Ws[k * DIM + j];
            p0 += hk * w2.x;
            p1 += hk * w2.y;
        }
    }

    const float2 b2 = *(const float2*)&hrW[(size_t)rel * DIM + j];
    const float2 c2 = *(const float2*)&qrW[(size_t)r_idx * DIM + j];
    p0 = fmaxf(p0 + b2.x + c2.x, 0.f);
    p1 = fmaxf(p1 + b2.y + c2.y, 0.f);

    const float2 ww = *(const float2*)&walpha_w[j];
    float s = p0 * ww.x + p1 * ww.y;
#pragma unroll
    for (int off = 32; off >= 1; off >>= 1)
        s += __shfl_xor(s, off, 64);

    const float alpha = 1.f / (1.f + expf(-(s + walpha_b[0])));

    if (valid) {
        const float m0 = alpha * (hv.x + rv.x);
        const float m1 = alpha * (hv.y + rv.y);
        atomicAdd(&agg[(size_t)obj * DIM + j], m0);
        atomicAdd(&agg[(size_t)obj * DIM + j + 1], m1);
        if (lane == 0) alpha_out[e] = alpha;
    }
}

// ---------------------------------------------------------------------------
__global__ __launch_bounds__(256) void nodes_kernel(
    const int* __restrict__ nodes, float* __restrict__ out, int N)
{
    int i = blockIdx.x * 256 + threadIdx.x;
    if (i < N) {
        int v = nodes[(size_t)i * 2 + 1];
        out[i] = (v > -1 && v < N_NODE_C + 1) ? 1.f : 0.f;
    }
}

// ---------------------------------------------------------------------------
extern "C" void kernel_launch(void* const* d_in, const int* in_sizes, int n_in,
                              void* d_out, int out_size, void* d_ws, size_t ws_size,
                              hipStream_t stream)
{
    const int*   q_rel    = (const int*)d_in[1];
    const float* hidden   = (const float*)d_in[2];
    const int*   edges    = (const int*)d_in[3];
    const int*   nodes    = (const int*)d_in[4];
    const float* rela     = (const float*)d_in[5];
    const float* Ws       = (const float*)d_in[6];
    const float* Wr       = (const float*)d_in[7];
    const float* Wqr_w    = (const float*)d_in[8];
    const float* Wqr_b    = (const float*)d_in[9];
    const float* walpha_w = (const float*)d_in[10];
    const float* walpha_b = (const float*)d_in[11];
    const float* Wh       = (const float*)d_in[12];

    const int B  = in_sizes[1];
    const int N  = in_sizes[2] / DIM;
    const int E  = in_sizes[3] / 6;
    const int RV = in_sizes[5] / DIM;

    float* out       = (float*)d_out;
    float* agg       = out;                          // N*128
    float* alpha_out = out + (size_t)N * DIM;        // E
    float* samp      = alpha_out + (size_t)E;        // N

    // Workspace layout.
    float* qrW = (float*)d_ws;                       // B x 128
    float* hrW = qrW + (size_t)B * DIM;              // RV x 128
    float* hsW = hrW + (size_t)RV * DIM;             // N x 128
    int*   deg    = (int*)(hsW + (size_t)N * DIM);   // N
    int*   offs   = deg + N;                         // N
    int*   cursor = offs + N;                        // N
    int*   sorted = cursor + N;                      // E
    int*   bsum   = sorted + E;                      // 128

    const size_t need_small = ((size_t)B + (size_t)RV) * DIM * sizeof(float);
    const size_t need_full  = need_small + (size_t)N * DIM * sizeof(float);
    const size_t need_sort  = need_full + ((size_t)3 * N + E + 128) * sizeof(int);

    proj_small<<<B + RV, 128, 0, stream>>>(q_rel, rela, Wqr_w, Wqr_b, Wr, qrW, hrW, B);

    if (ws_size >= need_sort) {
        // --- sorted pull path: no float atomics, no big memset ---
        gemm_n128<<<(N + 63) / 64, 256, 0, stream>>>(hidden, Ws, hsW, N);

        hipMemsetAsync(deg, 0, (size_t)N * sizeof(int), stream);
        hist_kernel<<<(E + 255) / 256, 256, 0, stream>>>(edges, deg, E);

        const int nb = (N + 2047) / 2048;            // <= 128 (bsum capacity)
        scan1_kernel<<<nb, 256, 0, stream>>>(deg, offs, bsum, N);
        scan2_kernel<<<1, 64, 0, stream>>>(bsum, nb);
        scan3_kernel<<<(N + 255) / 256, 256, 0, stream>>>(offs, cursor, bsum, N);
        scatter_kernel<<<(E + 255) / 256, 256, 0, stream>>>(edges, cursor, sorted, E);

        node_agg_kernel<<<(N + 3) / 4, 256, 0, stream>>>(
            edges, hidden, rela, hsW, qrW, hrW, walpha_w, walpha_b,
            deg, offs, sorted, agg, alpha_out, N);
    } else {
        // --- fallback: push-style with atomics (round-5 behavior) ---
        hipMemsetAsync(agg, 0, (size_t)N * DIM * sizeof(float), stream);
        if (ws_size >= need_full) {
            gemm_n128<<<(N + 63) / 64, 256, 0, stream>>>(hidden, Ws, hsW, N);
            edge_kernel<0><<<(E + 3) / 4, 256, 0, stream>>>(
                edges, hidden, rela, Ws, hsW, qrW, hrW, walpha_w, walpha_b,
                agg, alpha_out, E);
        } else {
            edge_kernel<1><<<(E + 3) / 4, 256, 0, stream>>>(
                edges, hidden, rela, Ws, hsW, qrW, hrW, walpha_w, walpha_b,
                agg, alpha_out, E);
        }
    }

    // hidden_new = agg @ Wh, in place over d_out[0 : N*128].
    gemm_n128<<<(N + 63) / 64, 256, 0, stream>>>(agg, Wh, out, N);

    nodes_kernel<<<(N + 255) / 256, 256, 0, stream>>>(nodes, samp, N);
}

// Round 7
// 382.113 us; speedup vs baseline: 15.4134x; 1.0824x over previous
//
#include <hip/hip_runtime.h>
#include <hip/hip_bf16.h>
#include <math.h>

// Problem constants (from reference): D = ATTN = 128, N_NODE = 100000.
#define DIM 128
#define N_NODE_C 100000

// ---------------------------------------------------------------------------
// Small projections: qrW[b] = rela_embed[q_rel[b]] @ Wqr_w + Wqr_b   (B rows)
//                    hrW[r] = rela_embed[r]        @ Wr             (RV rows)
// ---------------------------------------------------------------------------
__global__ __launch_bounds__(128) void proj_small(
    const int* __restrict__ q_rel,
    const float* __restrict__ rela,
    const float* __restrict__ Wqr_w,
    const float* __restrict__ Wqr_b,
    const float* __restrict__ Wr,
    float* __restrict__ qrW,
    float* __restrict__ hrW,
    int B)
{
    __shared__ float emb[DIM];
    const int blk = blockIdx.x;
    const int j   = threadIdx.x;

    const float* W;
    float* out;
    float bias = 0.f;
    int row;
    if (blk < B) {
        row  = q_rel[blk];
        W    = Wqr_w;
        out  = qrW + (size_t)blk * DIM;
        bias = Wqr_b[j];
    } else {
        row = blk - B;
        W   = Wr;
        out = hrW + (size_t)(blk - B) * DIM;
    }
    emb[j] = rela[(size_t)row * DIM + j];
    __syncthreads();

    float acc = bias;
#pragma unroll 8
    for (int k = 0; k < DIM; ++k)
        acc += emb[k] * W[k * DIM + j];
    out[j] = acc;
}

// ---------------------------------------------------------------------------
// C[M x 128] = A[M x 128] @ W[128 x 128]   (fp32). No-spill version.
// In-place safe (C == A): block stages its 64 rows in LDS, disjoint rows.
// ---------------------------------------------------------------------------
__global__ __launch_bounds__(256, 3) void gemm_n128(
    const float* A,
    const float* __restrict__ W,
    float* C,
    int M)
{
    __shared__ __align__(16) float Alds[64][DIM];
    __shared__ __align__(16) float Wlds[32][DIM];

    const int t    = threadIdx.x;
    const int row0 = blockIdx.x * 64;
    const int tx   = t & 31;
    const int ty   = t >> 5;

#pragma unroll
    for (int p = 0; p < 8; ++p) {
        int idx = p * 1024 + t * 4;
        int r   = idx >> 7;
        int c   = idx & 127;
        int gr  = row0 + r;
        if (gr >= M) gr = M - 1;
        *(float4*)&Alds[r][c] = *(const float4*)&A[(size_t)gr * DIM + c];
    }

    float acc[8][4] = {};

    for (int kk = 0; kk < 4; ++kk) {
        __syncthreads();
        {
            const float* Wg = W + (size_t)kk * 32 * DIM;
#pragma unroll
            for (int p = 0; p < 4; ++p) {
                int idx = p * 1024 + t * 4;
                *(float4*)&Wlds[idx >> 7][idx & 127] = *(const float4*)&Wg[idx];
            }
        }
        __syncthreads();

#pragma unroll 2
        for (int k4 = 0; k4 < 32; k4 += 4) {
            const float4 w0 = *(const float4*)&Wlds[k4 + 0][tx * 4];
            const float4 w1 = *(const float4*)&Wlds[k4 + 1][tx * 4];
            const float4 w2 = *(const float4*)&Wlds[k4 + 2][tx * 4];
            const float4 w3 = *(const float4*)&Wlds[k4 + 3][tx * 4];
#pragma unroll
            for (int i = 0; i < 8; ++i) {
                const float4 a = *(const float4*)&Alds[ty * 8 + i][kk * 32 + k4];
                acc[i][0] = fmaf(a.w, w3.x, fmaf(a.z, w2.x, fmaf(a.y, w1.x, fmaf(a.x, w0.x, acc[i][0]))));
                acc[i][1] = fmaf(a.w, w3.y, fmaf(a.z, w2.y, fmaf(a.y, w1.y, fmaf(a.x, w0.y, acc[i][1]))));
                acc[i][2] = fmaf(a.w, w3.z, fmaf(a.z, w2.z, fmaf(a.y, w1.z, fmaf(a.x, w0.z, acc[i][2]))));
                acc[i][3] = fmaf(a.w, w3.w, fmaf(a.z, w2.w, fmaf(a.y, w1.w, fmaf(a.x, w0.w, acc[i][3]))));
            }
        }
    }
    __syncthreads();

#pragma unroll
    for (int i = 0; i < 8; ++i) {
        int gr = row0 + ty * 8 + i;
        if (gr < M) {
            float4 v = make_float4(acc[i][0], acc[i][1], acc[i][2], acc[i][3]);
            *(float4*)&C[(size_t)gr * DIM + tx * 4] = v;
        }
    }
}

// ---------------------------------------------------------------------------
// Counting sort by obj: hist -> exclusive scan (3 kernels) -> scatter.
// ---------------------------------------------------------------------------
__global__ __launch_bounds__(256) void hist_kernel(
    const int* __restrict__ edges, int* __restrict__ deg, int E)
{
    int i = blockIdx.x * 256 + threadIdx.x;
    if (i < E) atomicAdd(&deg[edges[(size_t)i * 6 + 5]], 1);
}

__global__ __launch_bounds__(256) void scan1_kernel(
    const int* __restrict__ in, int* __restrict__ out,
    int* __restrict__ bsum, int n)
{
    __shared__ int ts[256];
    const int tid  = threadIdx.x;
    const int base = blockIdx.x * 2048 + tid * 8;

    int v[8];
    int run = 0;
#pragma unroll
    for (int i = 0; i < 8; ++i) {
        int x = (base + i < n) ? in[base + i] : 0;
        v[i] = run;
        run += x;
    }
    ts[tid] = run;
    __syncthreads();
    for (int off = 1; off < 256; off <<= 1) {
        int x = (tid >= off) ? ts[tid - off] : 0;
        __syncthreads();
        ts[tid] += x;
        __syncthreads();
    }
    const int excl = ts[tid] - run;
#pragma unroll
    for (int i = 0; i < 8; ++i)
        if (base + i < n) out[base + i] = v[i] + excl;
    if (tid == 255) bsum[blockIdx.x] = ts[255];
}

__global__ void scan2_kernel(int* __restrict__ bsum, int nb)
{
    if (blockIdx.x == 0 && threadIdx.x == 0) {
        int run = 0;
        for (int i = 0; i < nb; ++i) { int x = bsum[i]; bsum[i] = run; run += x; }
    }
}

__global__ __launch_bounds__(256) void scan3_kernel(
    int* __restrict__ offs, int* __restrict__ cursor,
    const int* __restrict__ bsum, int n)
{
    int i = blockIdx.x * 256 + threadIdx.x;
    if (i < n) {
        int v = offs[i] + bsum[i >> 11];
        offs[i]   = v;
        cursor[i] = v;
    }
}

__global__ __launch_bounds__(256) void scatter_kernel(
    const int* __restrict__ edges, int* __restrict__ cursor,
    int* __restrict__ sorted, int E)
{
    int i = blockIdx.x * 256 + threadIdx.x;
    if (i < E) {
        int obj = edges[(size_t)i * 6 + 5];
        int pos = atomicAdd(&cursor[obj], 1);
        sorted[pos] = i;
    }
}

// ---------------------------------------------------------------------------
// Pull-style aggregation, 4 edges per wave concurrently.
// Wave = one node. Quarters (16 lanes) each own one edge per iteration;
// each lane covers 8 columns (2x float4). Dot-reduce = 4 shuffle stages
// within the quarter; cross-quarter combine once at the end; one clean
// 512 B row store. Inactive quarters are exec-masked (no wasted fetch).
// ---------------------------------------------------------------------------
__global__ __launch_bounds__(256) void node_agg_kernel(
    const int* __restrict__ edges,
    const float* __restrict__ hidden,
    const float* __restrict__ rela,
    const float* __restrict__ hsW,
    const float* __restrict__ qrW,
    const float* __restrict__ hrW,
    const float* __restrict__ walpha_w,
    const float* __restrict__ walpha_b,
    const int* __restrict__ deg,
    const int* __restrict__ offs,
    const int* __restrict__ sorted,
    float* __restrict__ agg,
    float* __restrict__ alpha_out,
    int N)
{
    const int widx = threadIdx.x >> 6;
    const int lane = threadIdx.x & 63;
    const int o    = blockIdx.x * 4 + widx;
    if (o >= N) return;

    const int q   = lane >> 4;          // quarter 0..3 (one edge each)
    const int l16 = lane & 15;
    const int j   = l16 * 8;            // 8 columns per lane

    const int d = deg[o];
    const int s = offs[o];

    const float4 wwA = *(const float4*)&walpha_w[j];
    const float4 wwB = *(const float4*)&walpha_w[j + 4];
    const float  wb  = walpha_b[0];

    float4 accA = make_float4(0.f, 0.f, 0.f, 0.f);
    float4 accB = make_float4(0.f, 0.f, 0.f, 0.f);

    for (int k = 0; k < d; k += 4) {
        const int kk = k + q;
        if (kk < d) {                   // uniform within the 16-lane quarter
            const int e     = sorted[s + kk];
            const int r_idx = edges[(size_t)e * 6 + 0];
            const int rel   = edges[(size_t)e * 6 + 2];
            const int sub   = edges[(size_t)e * 6 + 4];

            const float4 hvA = *(const float4*)&hidden[(size_t)sub * DIM + j];
            const float4 hvB = *(const float4*)&hidden[(size_t)sub * DIM + j + 4];
            const float4 rvA = *(const float4*)&rela[(size_t)rel * DIM + j];
            const float4 rvB = *(const float4*)&rela[(size_t)rel * DIM + j + 4];
            const float4 pwA = *(const float4*)&hsW[(size_t)sub * DIM + j];
            const float4 pwB = *(const float4*)&hsW[(size_t)sub * DIM + j + 4];
            const float4 bA  = *(const float4*)&hrW[(size_t)rel * DIM + j];
            const float4 bB  = *(const float4*)&hrW[(size_t)rel * DIM + j + 4];
            const float4 cA  = *(const float4*)&qrW[(size_t)r_idx * DIM + j];
            const float4 cB  = *(const float4*)&qrW[(size_t)r_idx * DIM + j + 4];

            float sdot =
                fmaxf(pwA.x + bA.x + cA.x, 0.f) * wwA.x +
                fmaxf(pwA.y + bA.y + cA.y, 0.f) * wwA.y +
                fmaxf(pwA.z + bA.z + cA.z, 0.f) * wwA.z +
                fmaxf(pwA.w + bA.w + cA.w, 0.f) * wwA.w +
                fmaxf(pwB.x + bB.x + cB.x, 0.f) * wwB.x +
                fmaxf(pwB.y + bB.y + cB.y, 0.f) * wwB.y +
                fmaxf(pwB.z + bB.z + cB.z, 0.f) * wwB.z +
                fmaxf(pwB.w + bB.w + cB.w, 0.f) * wwB.w;

            // Reduce across the 16-lane quarter.
#pragma unroll
            for (int off = 8; off >= 1; off >>= 1)
                sdot += __shfl_xor(sdot, off, 16);

            const float alpha = 1.f / (1.f + expf(-(sdot + wb)));

            accA.x += alpha * (hvA.x + rvA.x);
            accA.y += alpha * (hvA.y + rvA.y);
            accA.z += alpha * (hvA.z + rvA.z);
            accA.w += alpha * (hvA.w + rvA.w);
            accB.x += alpha * (hvB.x + rvB.x);
            accB.y += alpha * (hvB.y + rvB.y);
            accB.z += alpha * (hvB.z + rvB.z);
            accB.w += alpha * (hvB.w + rvB.w);

            if (l16 == 0) alpha_out[e] = alpha;
        }
    }

    // Combine the 4 quarters (same columns live at lane ^16, ^32).
#pragma unroll
    for (int off = 16; off <= 32; off <<= 1) {
        accA.x += __shfl_xor(accA.x, off, 64);
        accA.y += __shfl_xor(accA.y, off, 64);
        accA.z += __shfl_xor(accA.z, off, 64);
        accA.w += __shfl_xor(accA.w, off, 64);
        accB.x += __shfl_xor(accB.x, off, 64);
        accB.y += __shfl_xor(accB.y, off, 64);
        accB.z += __shfl_xor(accB.z, off, 64);
        accB.w += __shfl_xor(accB.w, off, 64);
    }

    if (q == 0) {
        *(float4*)&agg[(size_t)o * DIM + j]     = accA;
        *(float4*)&agg[(size_t)o * DIM + j + 4] = accB;
    }
}

// ---------------------------------------------------------------------------
// Fallback (round-5) push-style edge kernel with f32 atomics.
// ---------------------------------------------------------------------------
template <int MODE>
__global__ __launch_bounds__(256) void edge_kernel(
    const int* __restrict__ edges,
    const float* __restrict__ hidden,
    const float* __restrict__ rela,
    const float* __restrict__ Ws,
    const float* __restrict__ hsW,
    const float* __restrict__ qrW,
    const float* __restrict__ hrW,
    const float* __restrict__ walpha_w,
    const float* __restrict__ walpha_b,
    float* __restrict__ agg,
    float* __restrict__ alpha_out,
    int E)
{
    const int widx = threadIdx.x >> 6;
    const int lane = threadIdx.x & 63;
    const int e    = blockIdx.x * 4 + widx;
    const bool valid = (e < E);
    const int ec   = valid ? e : 0;

    const int r_idx = edges[(size_t)ec * 6 + 0];
    const int rel   = edges[(size_t)ec * 6 + 2];
    const int sub   = edges[(size_t)ec * 6 + 4];
    const int obj   = edges[(size_t)ec * 6 + 5];

    const int j = lane * 2;

    const float2 hv = *(const float2*)&hidden[(size_t)sub * DIM + j];
    const float2 rv = *(const float2*)&rela[(size_t)rel * DIM + j];

    float p0, p1;
    if (MODE == 0) {
        float2 a = *(const float2*)&hsW[(size_t)sub * DIM + j];
        p0 = a.x;
        p1 = a.y;
    } else {
        __shared__ float hrow[4][DIM];
        *(float2*)&hrow[widx][j] = hv;
        __syncthreads();
        p0 = 0.f;
        p1 = 0.f;
#pragma unroll 4
        for (int k = 0; k < DIM; ++k) {
            float hk  = hrow[widx][k];
            float2 w2 = *(const float2*)&Ws[k * DIM + j];
            p0 += hk * w2.x;
            p1 += hk * w2.y;
        }
    }

    const float2 b2 = *(const float2*)&hrW[(size_t)rel * DIM + j];
    const float2 c2 = *(const float2*)&qrW[(size_t)r_idx * DIM + j];
    p0 = fmaxf(p0 + b2.x + c2.x, 0.f);
    p1 = fmaxf(p1 + b2.y + c2.y, 0.f);

    const float2 ww = *(const float2*)&walpha_w[j];
    float s = p0 * ww.x + p1 * ww.y;
#pragma unroll
    for (int off = 32; off >= 1; off >>= 1)
        s += __shfl_xor(s, off, 64);

    const float alpha = 1.f / (1.f + expf(-(s + walpha_b[0])));

    if (valid) {
        const float m0 = alpha * (hv.x + rv.x);
        const float m1 = alpha * (hv.y + rv.y);
        atomicAdd(&agg[(size_t)obj * DIM + j], m0);
        atomicAdd(&agg[(size_t)obj * DIM + j + 1], m1);
        if (lane == 0) alpha_out[e] = alpha;
    }
}

// ---------------------------------------------------------------------------
__global__ __launch_bounds__(256) void nodes_kernel(
    const int* __restrict__ nodes, float* __restrict__ out, int N)
{
    int i = blockIdx.x * 256 + threadIdx.x;
    if (i < N) {
        int v = nodes[(size_t)i * 2 + 1];
        out[i] = (v > -1 && v < N_NODE_C + 1) ? 1.f : 0.f;
    }
}

// ---------------------------------------------------------------------------
extern "C" void kernel_launch(void* const* d_in, const int* in_sizes, int n_in,
                              void* d_out, int out_size, void* d_ws, size_t ws_size,
                              hipStream_t stream)
{
    const int*   q_rel    = (const int*)d_in[1];
    const float* hidden   = (const float*)d_in[2];
    const int*   edges    = (const int*)d_in[3];
    const int*   nodes    = (const int*)d_in[4];
    const float* rela     = (const float*)d_in[5];
    const float* Ws       = (const float*)d_in[6];
    const float* Wr       = (const float*)d_in[7];
    const float* Wqr_w    = (const float*)d_in[8];
    const float* Wqr_b    = (const float*)d_in[9];
    const float* walpha_w = (const float*)d_in[10];
    const float* walpha_b = (const float*)d_in[11];
    const float* Wh       = (const float*)d_in[12];

    const int B  = in_sizes[1];
    const int N  = in_sizes[2] / DIM;
    const int E  = in_sizes[3] / 6;
    const int RV = in_sizes[5] / DIM;

    float* out       = (float*)d_out;
    float* agg       = out;                          // N*128
    float* alpha_out = out + (size_t)N * DIM;        // E
    float* samp      = alpha_out + (size_t)E;        // N

    // Workspace layout.
    float* qrW = (float*)d_ws;                       // B x 128
    float* hrW = qrW + (size_t)B * DIM;              // RV x 128
    float* hsW = hrW + (size_t)RV * DIM;             // N x 128
    int*   deg    = (int*)(hsW + (size_t)N * DIM);   // N
    int*   offs   = deg + N;                         // N
    int*   cursor = offs + N;                        // N
    int*   sorted = cursor + N;                      // E
    int*   bsum   = sorted + E;                      // 128

    const size_t need_small = ((size_t)B + (size_t)RV) * DIM * sizeof(float);
    const size_t need_full  = need_small + (size_t)N * DIM * sizeof(float);
    const size_t need_sort  = need_full + ((size_t)3 * N + E + 128) * sizeof(int);

    proj_small<<<B + RV, 128, 0, stream>>>(q_rel, rela, Wqr_w, Wqr_b, Wr, qrW, hrW, B);

    if (ws_size >= need_sort) {
        // --- sorted pull path: no float atomics, no big memset ---
        gemm_n128<<<(N + 63) / 64, 256, 0, stream>>>(hidden, Ws, hsW, N);

        hipMemsetAsync(deg, 0, (size_t)N * sizeof(int), stream);
        hist_kernel<<<(E + 255) / 256, 256, 0, stream>>>(edges, deg, E);

        const int nb = (N + 2047) / 2048;            // <= 128 (bsum capacity)
        scan1_kernel<<<nb, 256, 0, stream>>>(deg, offs, bsum, N);
        scan2_kernel<<<1, 64, 0, stream>>>(bsum, nb);
        scan3_kernel<<<(N + 255) / 256, 256, 0, stream>>>(offs, cursor, bsum, N);
        scatter_kernel<<<(E + 255) / 256, 256, 0, stream>>>(edges, cursor, sorted, E);

        node_agg_kernel<<<(N + 3) / 4, 256, 0, stream>>>(
            edges, hidden, rela, hsW, qrW, hrW, walpha_w, walpha_b,
            deg, offs, sorted, agg, alpha_out, N);
    } else {
        // --- fallback: push-style with atomics (round-5 behavior) ---
        hipMemsetAsync(agg, 0, (size_t)N * DIM * sizeof(float), stream);
        if (ws_size >= need_full) {
            gemm_n128<<<(N + 63) / 64, 256, 0, stream>>>(hidden, Ws, hsW, N);
            edge_kernel<0><<<(E + 3) / 4, 256, 0, stream>>>(
                edges, hidden, rela, Ws, hsW, qrW, hrW, walpha_w, walpha_b,
                agg, alpha_out, E);
        } else {
            edge_kernel<1><<<(E + 3) / 4, 256, 0, stream>>>(
                edges, hidden, rela, Ws, hsW, qrW, hrW, walpha_w, walpha_b,
                agg, alpha_out, E);
        }
    }

    // hidden_new = agg @ Wh, in place over d_out[0 : N*128].
    gemm_n128<<<(N + 63) / 64, 256, 0, stream>>>(agg, Wh, out, N);

    nodes_kernel<<<(N + 255) / 256, 256, 0, stream>>>(nodes, samp, N);
}

// Round 8
// 258.186 us; speedup vs baseline: 22.8116x; 1.4800x over previous
//
#include <hip/hip_runtime.h>
#include <hip/hip_bf16.h>
#include <math.h>

// Problem constants (from reference): D = ATTN = 128, N_NODE = 100000.
#define DIM 128
#define N_NODE_C 100000

typedef __attribute__((ext_vector_type(8))) short  bf16x8;
typedef __attribute__((ext_vector_type(4))) float  f32x4;
typedef __attribute__((ext_vector_type(8))) unsigned short u16x8;

__device__ inline unsigned short f2bf_rne(float f) {
    unsigned u = __float_as_uint(f);
    return (unsigned short)((u + 0x7FFFu + ((u >> 16) & 1u)) >> 16);
}
__device__ inline float bf2f(unsigned short u) {
    return __uint_as_float(((unsigned)u) << 16);
}

// ---------------------------------------------------------------------------
// Small projections: qrW[b] = rela_embed[q_rel[b]] @ Wqr_w + Wqr_b   (B rows)
//                    hrW[r] = rela_embed[r]        @ Wr             (RV rows)
// ---------------------------------------------------------------------------
__global__ __launch_bounds__(128) void proj_small(
    const int* __restrict__ q_rel,
    const float* __restrict__ rela,
    const float* __restrict__ Wqr_w,
    const float* __restrict__ Wqr_b,
    const float* __restrict__ Wr,
    float* __restrict__ qrW,
    float* __restrict__ hrW,
    int B)
{
    __shared__ float emb[DIM];
    const int blk = blockIdx.x;
    const int j   = threadIdx.x;

    const float* W;
    float* out;
    float bias = 0.f;
    int row;
    if (blk < B) {
        row  = q_rel[blk];
        W    = Wqr_w;
        out  = qrW + (size_t)blk * DIM;
        bias = Wqr_b[j];
    } else {
        row = blk - B;
        W   = Wr;
        out = hrW + (size_t)(blk - B) * DIM;
    }
    emb[j] = rela[(size_t)row * DIM + j];
    __syncthreads();

    float acc = bias;
#pragma unroll 8
    for (int k = 0; k < DIM; ++k)
        acc += emb[k] * W[k * DIM + j];
    out[j] = acc;
}

// ---------------------------------------------------------------------------
// Pack W[128x128] (f32) into mfma_f32_16x16x32_bf16 B-fragment layout:
// Wpack[ct*256 + kb*64 + lane] = uint4 of 8 bf16, elem i = W[kb*32+(lane>>4)*8+i][ct*16+(lane&15)].
// Launch: 8 blocks x 256 threads (2048 fragments).
// ---------------------------------------------------------------------------
__global__ __launch_bounds__(256) void pack_w(
    const float* __restrict__ W, uint4* __restrict__ Wpack)
{
    const int id   = blockIdx.x * 256 + threadIdx.x;   // 0..2047
    const int ct   = id >> 8;
    const int kb   = (id >> 6) & 3;
    const int lane = id & 63;
    const int col  = ct * 16 + (lane & 15);
    const int k0   = kb * 32 + (lane >> 4) * 8;

    unsigned v[4];
#pragma unroll
    for (int p = 0; p < 4; ++p) {
        unsigned lo = f2bf_rne(W[(size_t)(k0 + 2 * p)     * DIM + col]);
        unsigned hi = f2bf_rne(W[(size_t)(k0 + 2 * p + 1) * DIM + col]);
        v[p] = lo | (hi << 16);
    }
    Wpack[id] = make_uint4(v[0], v[1], v[2], v[3]);
}

// ---------------------------------------------------------------------------
// C[M x 128] = A[M x 128 (f32)] @ W[128 x 128] via bf16 MFMA (fp32 accum).
// Block = 4 waves, wave = 16 rows x 128 cols (8 col-tiles x 4 K-blocks).
// A converted f32->bf16 (RNE) in registers. Wpack staged in LDS (32 KB).
// C/D layout (HW-verified): col = lane&15, row = (lane>>4)*4 + reg.
// In-place safe (C == A): each wave reads its own 16 rows fully through
// registers before storing those same rows; blocks touch disjoint rows.
// BF16_OUT: store C as bf16 (for hsW) else f32.
// ---------------------------------------------------------------------------
template <int BF16_OUT>
__global__ __launch_bounds__(256) void gemm_mfma(
    const float* A, const uint4* __restrict__ Wpack, void* Cv, int M)
{
    __shared__ uint4 wlds[2048];   // [ct][kb][lane], 32 KB
    const int t = threadIdx.x;
#pragma unroll
    for (int p = 0; p < 8; ++p)
        wlds[p * 256 + t] = Wpack[p * 256 + t];
    __syncthreads();

    const int wave = t >> 6;
    const int lane = t & 63;
    const int r    = lane & 15;
    const int g    = lane >> 4;
    const int row0 = blockIdx.x * 64 + wave * 16;

    int arow = row0 + r;
    if (arow >= M) arow = M - 1;
    const float* Ap = A + (size_t)arow * DIM + g * 8;

    bf16x8 afrag[4];
#pragma unroll
    for (int kb = 0; kb < 4; ++kb) {
        const float4 lo = *(const float4*)(Ap + kb * 32);
        const float4 hi = *(const float4*)(Ap + kb * 32 + 4);
        bf16x8 a;
        a[0] = (short)f2bf_rne(lo.x); a[1] = (short)f2bf_rne(lo.y);
        a[2] = (short)f2bf_rne(lo.z); a[3] = (short)f2bf_rne(lo.w);
        a[4] = (short)f2bf_rne(hi.x); a[5] = (short)f2bf_rne(hi.y);
        a[6] = (short)f2bf_rne(hi.z); a[7] = (short)f2bf_rne(hi.w);
        afrag[kb] = a;
    }

#pragma unroll
    for (int ct = 0; ct < 8; ++ct) {
        f32x4 acc = {0.f, 0.f, 0.f, 0.f};
#pragma unroll
        for (int kb = 0; kb < 4; ++kb) {
            bf16x8 b = *(bf16x8*)&wlds[ct * 256 + kb * 64 + lane];
            acc = __builtin_amdgcn_mfma_f32_16x16x32_bf16(afrag[kb], b, acc, 0, 0, 0);
        }
        const int col = ct * 16 + r;
#pragma unroll
        for (int j = 0; j < 4; ++j) {
            const int row = row0 + g * 4 + j;
            if (row < M) {
                if (BF16_OUT)
                    ((unsigned short*)Cv)[(size_t)row * DIM + col] = f2bf_rne(acc[j]);
                else
                    ((float*)Cv)[(size_t)row * DIM + col] = acc[j];
            }
        }
    }
}

// ---------------------------------------------------------------------------
// Fallback fp32 GEMM (no spill), used only if workspace is too small.
// ---------------------------------------------------------------------------
__global__ __launch_bounds__(256, 3) void gemm_n128(
    const float* A,
    const float* __restrict__ W,
    float* C,
    int M)
{
    __shared__ __align__(16) float Alds[64][DIM];
    __shared__ __align__(16) float Wlds[32][DIM];

    const int t    = threadIdx.x;
    const int row0 = blockIdx.x * 64;
    const int tx   = t & 31;
    const int ty   = t >> 5;

#pragma unroll
    for (int p = 0; p < 8; ++p) {
        int idx = p * 1024 + t * 4;
        int r   = idx >> 7;
        int c   = idx & 127;
        int gr  = row0 + r;
        if (gr >= M) gr = M - 1;
        *(float4*)&Alds[r][c] = *(const float4*)&A[(size_t)gr * DIM + c];
    }

    float acc[8][4] = {};

    for (int kk = 0; kk < 4; ++kk) {
        __syncthreads();
        {
            const float* Wg = W + (size_t)kk * 32 * DIM;
#pragma unroll
            for (int p = 0; p < 4; ++p) {
                int idx = p * 1024 + t * 4;
                *(float4*)&Wlds[idx >> 7][idx & 127] = *(const float4*)&Wg[idx];
            }
        }
        __syncthreads();

#pragma unroll 2
        for (int k4 = 0; k4 < 32; k4 += 4) {
            const float4 w0 = *(const float4*)&Wlds[k4 + 0][tx * 4];
            const float4 w1 = *(const float4*)&Wlds[k4 + 1][tx * 4];
            const float4 w2 = *(const float4*)&Wlds[k4 + 2][tx * 4];
            const float4 w3 = *(const float4*)&Wlds[k4 + 3][tx * 4];
#pragma unroll
            for (int i = 0; i < 8; ++i) {
                const float4 a = *(const float4*)&Alds[ty * 8 + i][kk * 32 + k4];
                acc[i][0] = fmaf(a.w, w3.x, fmaf(a.z, w2.x, fmaf(a.y, w1.x, fmaf(a.x, w0.x, acc[i][0]))));
                acc[i][1] = fmaf(a.w, w3.y, fmaf(a.z, w2.y, fmaf(a.y, w1.y, fmaf(a.x, w0.y, acc[i][1]))));
                acc[i][2] = fmaf(a.w, w3.z, fmaf(a.z, w2.z, fmaf(a.y, w1.z, fmaf(a.x, w0.z, acc[i][2]))));
                acc[i][3] = fmaf(a.w, w3.w, fmaf(a.z, w2.w, fmaf(a.y, w1.w, fmaf(a.x, w0.w, acc[i][3]))));
            }
        }
    }
    __syncthreads();

#pragma unroll
    for (int i = 0; i < 8; ++i) {
        int gr = row0 + ty * 8 + i;
        if (gr < M) {
            float4 v = make_float4(acc[i][0], acc[i][1], acc[i][2], acc[i][3]);
            *(float4*)&C[(size_t)gr * DIM + tx * 4] = v;
        }
    }
}

// ---------------------------------------------------------------------------
// Counting sort by obj: hist -> exclusive scan (3 kernels) -> scatter.
// ---------------------------------------------------------------------------
__global__ __launch_bounds__(256) void hist_kernel(
    const int* __restrict__ edges, int* __restrict__ deg, int E)
{
    int i = blockIdx.x * 256 + threadIdx.x;
    if (i < E) atomicAdd(&deg[edges[(size_t)i * 6 + 5]], 1);
}

__global__ __launch_bounds__(256) void scan1_kernel(
    const int* __restrict__ in, int* __restrict__ out,
    int* __restrict__ bsum, int n)
{
    __shared__ int ts[256];
    const int tid  = threadIdx.x;
    const int base = blockIdx.x * 2048 + tid * 8;

    int v[8];
    int run = 0;
#pragma unroll
    for (int i = 0; i < 8; ++i) {
        int x = (base + i < n) ? in[base + i] : 0;
        v[i] = run;
        run += x;
    }
    ts[tid] = run;
    __syncthreads();
    for (int off = 1; off < 256; off <<= 1) {
        int x = (tid >= off) ? ts[tid - off] : 0;
        __syncthreads();
        ts[tid] += x;
        __syncthreads();
    }
    const int excl = ts[tid] - run;
#pragma unroll
    for (int i = 0; i < 8; ++i)
        if (base + i < n) out[base + i] = v[i] + excl;
    if (tid == 255) bsum[blockIdx.x] = ts[255];
}

__global__ void scan2_kernel(int* __restrict__ bsum, int nb)
{
    if (blockIdx.x == 0 && threadIdx.x == 0) {
        int run = 0;
        for (int i = 0; i < nb; ++i) { int x = bsum[i]; bsum[i] = run; run += x; }
    }
}

__global__ __launch_bounds__(256) void scan3_kernel(
    int* __restrict__ offs, int* __restrict__ cursor,
    const int* __restrict__ bsum, int n)
{
    int i = blockIdx.x * 256 + threadIdx.x;
    if (i < n) {
        int v = offs[i] + bsum[i >> 11];
        offs[i]   = v;
        cursor[i] = v;
    }
}

__global__ __launch_bounds__(256) void scatter_kernel(
    const int* __restrict__ edges, int* __restrict__ cursor,
    int* __restrict__ sorted, int E)
{
    int i = blockIdx.x * 256 + threadIdx.x;
    if (i < E) {
        int obj = edges[(size_t)i * 6 + 5];
        int pos = atomicAdd(&cursor[obj], 1);
        sorted[pos] = i;
    }
}

// ---------------------------------------------------------------------------
// Pull-style aggregation, 4 edges per wave concurrently; hsW read as bf16.
// Wave = one node; quarters (16 lanes) each own one edge per iteration;
// each lane covers 8 columns. One clean 512 B row store per node.
// ---------------------------------------------------------------------------
__global__ __launch_bounds__(256) void node_agg_kernel(
    const int* __restrict__ edges,
    const float* __restrict__ hidden,
    const float* __restrict__ rela,
    const unsigned short* __restrict__ hsWb,   // N x 128 bf16
    const float* __restrict__ qrW,
    const float* __restrict__ hrW,
    const float* __restrict__ walpha_w,
    const float* __restrict__ walpha_b,
    const int* __restrict__ deg,
    const int* __restrict__ offs,
    const int* __restrict__ sorted,
    float* __restrict__ agg,
    float* __restrict__ alpha_out,
    int N)
{
    const int widx = threadIdx.x >> 6;
    const int lane = threadIdx.x & 63;
    const int o    = blockIdx.x * 4 + widx;
    if (o >= N) return;

    const int q   = lane >> 4;          // quarter 0..3 (one edge each)
    const int l16 = lane & 15;
    const int j   = l16 * 8;            // 8 columns per lane

    const int d = deg[o];
    const int s = offs[o];

    const float4 wwA = *(const float4*)&walpha_w[j];
    const float4 wwB = *(const float4*)&walpha_w[j + 4];
    const float  wb  = walpha_b[0];

    float4 accA = make_float4(0.f, 0.f, 0.f, 0.f);
    float4 accB = make_float4(0.f, 0.f, 0.f, 0.f);

    for (int k = 0; k < d; k += 4) {
        const int kk = k + q;
        if (kk < d) {                   // uniform within the 16-lane quarter
            const int e     = sorted[s + kk];
            const int r_idx = edges[(size_t)e * 6 + 0];
            const int rel   = edges[(size_t)e * 6 + 2];
            const int sub   = edges[(size_t)e * 6 + 4];

            const float4 hvA = *(const float4*)&hidden[(size_t)sub * DIM + j];
            const float4 hvB = *(const float4*)&hidden[(size_t)sub * DIM + j + 4];
            const float4 rvA = *(const float4*)&rela[(size_t)rel * DIM + j];
            const float4 rvB = *(const float4*)&rela[(size_t)rel * DIM + j + 4];
            const u16x8  pw  = *(const u16x8*)&hsWb[(size_t)sub * DIM + j];
            const float4 bA  = *(const float4*)&hrW[(size_t)rel * DIM + j];
            const float4 bB  = *(const float4*)&hrW[(size_t)rel * DIM + j + 4];
            const float4 cA  = *(const float4*)&qrW[(size_t)r_idx * DIM + j];
            const float4 cB  = *(const float4*)&qrW[(size_t)r_idx * DIM + j + 4];

            float sdot =
                fmaxf(bf2f(pw[0]) + bA.x + cA.x, 0.f) * wwA.x +
                fmaxf(bf2f(pw[1]) + bA.y + cA.y, 0.f) * wwA.y +
                fmaxf(bf2f(pw[2]) + bA.z + cA.z, 0.f) * wwA.z +
                fmaxf(bf2f(pw[3]) + bA.w + cA.w, 0.f) * wwA.w +
                fmaxf(bf2f(pw[4]) + bB.x + cB.x, 0.f) * wwB.x +
                fmaxf(bf2f(pw[5]) + bB.y + cB.y, 0.f) * wwB.y +
                fmaxf(bf2f(pw[6]) + bB.z + cB.z, 0.f) * wwB.z +
                fmaxf(bf2f(pw[7]) + bB.w + cB.w, 0.f) * wwB.w;

            // Reduce across the 16-lane quarter.
#pragma unroll
            for (int off = 8; off >= 1; off >>= 1)
                sdot += __shfl_xor(sdot, off, 16);

            const float alpha = 1.f / (1.f + expf(-(sdot + wb)));

            accA.x += alpha * (hvA.x + rvA.x);
            accA.y += alpha * (hvA.y + rvA.y);
            accA.z += alpha * (hvA.z + rvA.z);
            accA.w += alpha * (hvA.w + rvA.w);
            accB.x += alpha * (hvB.x + rvB.x);
            accB.y += alpha * (hvB.y + rvB.y);
            accB.z += alpha * (hvB.z + rvB.z);
            accB.w += alpha * (hvB.w + rvB.w);

            if (l16 == 0) alpha_out[e] = alpha;
        }
    }

    // Combine the 4 quarters (same columns live at lane ^16, ^32).
#pragma unroll
    for (int off = 16; off <= 32; off <<= 1) {
        accA.x += __shfl_xor(accA.x, off, 64);
        accA.y += __shfl_xor(accA.y, off, 64);
        accA.z += __shfl_xor(accA.z, off, 64);
        accA.w += __shfl_xor(accA.w, off, 64);
        accB.x += __shfl_xor(accB.x, off, 64);
        accB.y += __shfl_xor(accB.y, off, 64);
        accB.z += __shfl_xor(accB.z, off, 64);
        accB.w += __shfl_xor(accB.w, off, 64);
    }

    if (q == 0) {
        *(float4*)&agg[(size_t)o * DIM + j]     = accA;
        *(float4*)&agg[(size_t)o * DIM + j + 4] = accB;
    }
}

// ---------------------------------------------------------------------------
// Fallback push-style edge kernel (inline hs @ Ws), f32 atomics.
// ---------------------------------------------------------------------------
__global__ __launch_bounds__(256) void edge_kernel_fb(
    const int* __restrict__ edges,
    const float* __restrict__ hidden,
    const float* __restrict__ rela,
    const float* __restrict__ Ws,
    const float* __restrict__ qrW,
    const float* __restrict__ hrW,
    const float* __restrict__ walpha_w,
    const float* __restrict__ walpha_b,
    float* __restrict__ agg,
    float* __restrict__ alpha_out,
    int E)
{
    const int widx = threadIdx.x >> 6;
    const int lane = threadIdx.x & 63;
    const int e    = blockIdx.x * 4 + widx;
    const bool valid = (e < E);
    const int ec   = valid ? e : 0;

    const int r_idx = edges[(size_t)ec * 6 + 0];
    const int rel   = edges[(size_t)ec * 6 + 2];
    const int sub   = edges[(size_t)ec * 6 + 4];
    const int obj   = edges[(size_t)ec * 6 + 5];

    const int j = lane * 2;

    const float2 hv = *(const float2*)&hidden[(size_t)sub * DIM + j];
    const float2 rv = *(const float2*)&rela[(size_t)rel * DIM + j];

    __shared__ float hrow[4][DIM];
    *(float2*)&hrow[widx][j] = hv;
    __syncthreads();
    float p0 = 0.f, p1 = 0.f;
#pragma unroll 4
    for (int k = 0; k < DIM; ++k) {
        float hk  = hrow[widx][k];
        float2 w2 = *(const float2*)&Ws[k * DIM + j];
        p0 += hk * w2.x;
        p1 += hk * w2.y;
    }

    const float2 b2 = *(const float2*)&hrW[(size_t)rel * DIM + j];
    const float2 c2 = *(const float2*)&qrW[(size_t)r_idx * DIM + j];
    p0 = fmaxf(p0 + b2.x + c2.x, 0.f);
    p1 = fmaxf(p1 + b2.y + c2.y, 0.f);

    const float2 ww = *(const float2*)&walpha_w[j];
    float s = p0 * ww.x + p1 * ww.y;
#pragma unroll
    for (int off = 32; off >= 1; off >>= 1)
        s += __shfl_xor(s, off, 64);

    const float alpha = 1.f / (1.f + expf(-(s + walpha_b[0])));

    if (valid) {
        const float m0 = alpha * (hv.x + rv.x);
        const float m1 = alpha * (hv.y + rv.y);
        atomicAdd(&agg[(size_t)obj * DIM + j], m0);
        atomicAdd(&agg[(size_t)obj * DIM + j + 1], m1);
        if (lane == 0) alpha_out[e] = alpha;
    }
}

// ---------------------------------------------------------------------------
__global__ __launch_bounds__(256) void nodes_kernel(
    const int* __restrict__ nodes, float* __restrict__ out, int N)
{
    int i = blockIdx.x * 256 + threadIdx.x;
    if (i < N) {
        int v = nodes[(size_t)i * 2 + 1];
        out[i] = (v > -1 && v < N_NODE_C + 1) ? 1.f : 0.f;
    }
}

// ---------------------------------------------------------------------------
extern "C" void kernel_launch(void* const* d_in, const int* in_sizes, int n_in,
                              void* d_out, int out_size, void* d_ws, size_t ws_size,
                              hipStream_t stream)
{
    const int*   q_rel    = (const int*)d_in[1];
    const float* hidden   = (const float*)d_in[2];
    const int*   edges    = (const int*)d_in[3];
    const int*   nodes    = (const int*)d_in[4];
    const float* rela     = (const float*)d_in[5];
    const float* Ws       = (const float*)d_in[6];
    const float* Wr       = (const float*)d_in[7];
    const float* Wqr_w    = (const float*)d_in[8];
    const float* Wqr_b    = (const float*)d_in[9];
    const float* walpha_w = (const float*)d_in[10];
    const float* walpha_b = (const float*)d_in[11];
    const float* Wh       = (const float*)d_in[12];

    const int B  = in_sizes[1];
    const int N  = in_sizes[2] / DIM;
    const int E  = in_sizes[3] / 6;
    const int RV = in_sizes[5] / DIM;

    float* out       = (float*)d_out;
    float* agg       = out;                          // N*128
    float* alpha_out = out + (size_t)N * DIM;        // E
    float* samp      = alpha_out + (size_t)E;        // N

    // Workspace layout.
    float* qrW = (float*)d_ws;                             // B x 128 f32
    float* hrW = qrW + (size_t)B * DIM;                    // RV x 128 f32
    uint4* wpack_s = (uint4*)(hrW + (size_t)RV * DIM);     // 2048 uint4 (32 KB)
    uint4* wpack_h = wpack_s + 2048;                       // 2048 uint4 (32 KB)
    unsigned short* hsWb = (unsigned short*)(wpack_h + 2048); // N x 128 bf16
    int*   deg    = (int*)(hsWb + (size_t)N * DIM);        // N
    int*   offs   = deg + N;                               // N
    int*   cursor = offs + N;                              // N
    int*   sorted = cursor + N;                            // E
    int*   bsum   = sorted + E;                            // 128

    const size_t need_sort =
        ((size_t)B + (size_t)RV) * DIM * sizeof(float) +
        2 * 2048 * sizeof(uint4) +
        (size_t)N * DIM * sizeof(unsigned short) +
        ((size_t)3 * N + E + 128) * sizeof(int);

    proj_small<<<B + RV, 128, 0, stream>>>(q_rel, rela, Wqr_w, Wqr_b, Wr, qrW, hrW, B);

    if (ws_size >= need_sort) {
        // --- primary: MFMA GEMMs + sorted pull aggregation ---
        pack_w<<<8, 256, 0, stream>>>(Ws, wpack_s);
        pack_w<<<8, 256, 0, stream>>>(Wh, wpack_h);

        gemm_mfma<1><<<(N + 63) / 64, 256, 0, stream>>>(hidden, wpack_s, hsWb, N);

        hipMemsetAsync(deg, 0, (size_t)N * sizeof(int), stream);
        hist_kernel<<<(E + 255) / 256, 256, 0, stream>>>(edges, deg, E);

        const int nb = (N + 2047) / 2048;            // <= 128 (bsum capacity)
        scan1_kernel<<<nb, 256, 0, stream>>>(deg, offs, bsum, N);
        scan2_kernel<<<1, 64, 0, stream>>>(bsum, nb);
        scan3_kernel<<<(N + 255) / 256, 256, 0, stream>>>(offs, cursor, bsum, N);
        scatter_kernel<<<(E + 255) / 256, 256, 0, stream>>>(edges, cursor, sorted, E);

        node_agg_kernel<<<(N + 3) / 4, 256, 0, stream>>>(
            edges, hidden, rela, hsWb, qrW, hrW, walpha_w, walpha_b,
            deg, offs, sorted, agg, alpha_out, N);

        // hidden_new = agg @ Wh, in place over d_out[0 : N*128].
        gemm_mfma<0><<<(N + 63) / 64, 256, 0, stream>>>(agg, wpack_h, out, N);
    } else {
        // --- fallback: push-style with atomics, fp32 GEMM ---
        hipMemsetAsync(agg, 0, (size_t)N * DIM * sizeof(float), stream);
        edge_kernel_fb<<<(E + 3) / 4, 256, 0, stream>>>(
            edges, hidden, rela, Ws, qrW, hrW, walpha_w, walpha_b,
            agg, alpha_out, E);
        gemm_n128<<<(N + 63) / 64, 256, 0, stream>>>(agg, Wh, out, N);
    }

    nodes_kernel<<<(N + 255) / 256, 256, 0, stream>>>(nodes, samp, N);
}